// Round 8
// baseline (186.474 us; speedup 1.0000x reference)
//
#include <hip/hip_runtime.h>
#include <hip/hip_bf16.h>

#define EMB    512
#define HEAD   64
#define SEQ    4096
#define NB     4
#define NSPLIT 8
#define LDX    72   // padded LDS row stride (144 B, 16B-aligned)

#define SL2E   0.18033688011112042f   // (1/sqrt(64)) * log2(e), folded into Wq

typedef __bf16 bf16x8 __attribute__((ext_vector_type(8)));
typedef float  f32x4  __attribute__((ext_vector_type(4)));

__device__ inline ushort4 cvt4(float4 v) {
    __hip_bfloat16 a = __float2bfloat16(v.x), b = __float2bfloat16(v.y);
    __hip_bfloat16 c = __float2bfloat16(v.z), d = __float2bfloat16(v.w);
    ushort4 r;
    r.x = *(unsigned short*)&a; r.y = *(unsigned short*)&b;
    r.z = *(unsigned short*)&c; r.w = *(unsigned short*)&d;
    return r;
}

__device__ inline bf16x8 cvt8(float4 a, float4 b) {
    union { ushort4 u[2]; bf16x8 v; } u;
    u.u[0] = cvt4(a);
    u.u[1] = cvt4(b);
    return u.v;
}

// ---------------------------------------------------------------------------
// One-shot W convert: [3][64][512] fp32 -> bf16; Wq pre-scaled by SL2E.
// ---------------------------------------------------------------------------
__global__ __launch_bounds__(256) void cvtw_kernel(
    const float* __restrict__ Wq, const float* __restrict__ Wk,
    const float* __restrict__ Wv, __hip_bfloat16* __restrict__ Wc)
{
    int idx   = blockIdx.x * 256 + threadIdx.x;
    int which = idx >> 13;
    int off   = (idx & 8191) * 4;
    const float* src = (which == 0) ? Wq : (which == 1) ? Wk : Wv;
    float s = (which == 0) ? SL2E : 1.0f;
    float4 v = *(const float4*)(src + off);
    v.x *= s; v.y *= s; v.z *= s; v.w *= s;
    *(ushort4*)(Wc + which * 64 * EMB + off) = cvt4(v);
}

// ---------------------------------------------------------------------------
// Projection v2 — NO LDS, NO BARRIERS: X A-frags load directly global->reg.
// R7 insight: LDS-staging X shared nothing (each wave only read back its own
// 16 rows); the barrier chain was the latency bottleneck. Direct X frag =
// 128 B contiguous per row, fully used (unlike R6's 16 B/row V scatter).
// Each wave owns 16 rows; per 64-col chunk: 4 float4 X loads + in-reg cvt +
// 8 L1-hot W frag loads + 8 MFMA, software-pipelined 1 chunk ahead.
// ---------------------------------------------------------------------------
__global__ __launch_bounds__(256) void proj_kernel(
    const float* __restrict__ q, const float* __restrict__ k, const float* __restrict__ v,
    const __hip_bfloat16* __restrict__ Wc,
    __hip_bfloat16* __restrict__ Qo, __hip_bfloat16* __restrict__ Ko,
    __hip_bfloat16* __restrict__ Vto)
{
    const int which = blockIdx.y;
    const float* __restrict__ x = (which == 0) ? q : (which == 1) ? k : v;
    const __hip_bfloat16* __restrict__ W = Wc + which * 64 * EMB;

    const int tid  = threadIdx.x;
    const int wave = tid >> 6, lane = tid & 63;
    const int l16  = lane & 15, quad = lane >> 4;
    const int r0   = blockIdx.x * 64;
    const int myrow = r0 + wave * 16 + l16;

    // lane's X row base + k-offset quad*8 (fp32)
    const float* __restrict__ xrow = x + (size_t)myrow * EMB + quad * 8;

    const f32x4 z = {0.f, 0.f, 0.f, 0.f};
    f32x4 acc[4] = {z, z, z, z};

    float4 xr[4];     // chunk's X: [st][2] float4 -> bf16x8 per st
    bf16x8 wf[8];     // chunk's W frags: [st][t]

#define LOADX(dst, e0)                                                        \
    _Pragma("unroll")                                                         \
    for (int st = 0; st < 2; ++st) {                                          \
        dst[st * 2 + 0] = *(const float4*)(xrow + (e0) + st * 32);            \
        dst[st * 2 + 1] = *(const float4*)(xrow + (e0) + st * 32 + 4);        \
    }

#define LOADW(dst, e0)                                                        \
    _Pragma("unroll")                                                         \
    for (int st = 0; st < 2; ++st)                                            \
        _Pragma("unroll")                                                     \
        for (int t = 0; t < 4; ++t)                                           \
            dst[st * 4 + t] = *(const bf16x8*)(W + (size_t)(t * 16 + l16) * EMB \
                                               + (e0) + st * 32 + quad * 8);

    LOADX(xr, 0);
    LOADW(wf, 0);

    #pragma unroll
    for (int c = 0; c < 8; ++c) {
        float4 xr2[4];
        bf16x8 wf2[8];
        if (c < 7) { LOADX(xr2, (c + 1) * 64); LOADW(wf2, (c + 1) * 64); }

        #pragma unroll
        for (int st = 0; st < 2; ++st) {
            bf16x8 a = cvt8(xr[st * 2 + 0], xr[st * 2 + 1]);
            #pragma unroll
            for (int t = 0; t < 4; ++t)
                acc[t] = __builtin_amdgcn_mfma_f32_16x16x32_bf16(a, wf[st * 4 + t], acc[t], 0, 0, 0);
        }

        if (c < 7) {
            #pragma unroll
            for (int j = 0; j < 4; ++j) xr[j] = xr2[j];
            #pragma unroll
            for (int j = 0; j < 8; ++j) wf[j] = wf2[j];
        }
    }
#undef LOADX
#undef LOADW

    #pragma unroll
    for (int t = 0; t < 4; ++t) {
        #pragma unroll
        for (int r = 0; r < 4; ++r) {
            int row = r0 + wave * 16 + quad * 4 + r;
            int h   = t * 16 + l16;
            __hip_bfloat16 val = __float2bfloat16(acc[t][r]);
            if (which == 0) {
                Qo[(size_t)row * HEAD + h] = val;   // already scaled via Wc
            } else if (which == 1) {
                Ko[(size_t)row * HEAD + h] = val;
            } else {
                int b = row >> 12, s = row & (SEQ - 1);
                Vto[((size_t)b * HEAD + h) * SEQ + s] = val;
            }
        }
    }
}

// ---------------------------------------------------------------------------
// Flash attention (R7 version, unchanged): 128 q-rows/block, K/V staged in
// LDS, Q frags direct from global, fixed-m softmax, l via MFMA-ones,
// disjoint fp32 partials per split.
// ---------------------------------------------------------------------------
__global__ __launch_bounds__(256) void attn_kernel(
    const __hip_bfloat16* __restrict__ Qb, const __hip_bfloat16* __restrict__ Kb,
    const __hip_bfloat16* __restrict__ Vt, float* __restrict__ Op,
    float* __restrict__ lp)
{
    __shared__ __hip_bfloat16 Ks[64][LDX];
    __shared__ __hip_bfloat16 Vs[64][LDX];    // V^T tile [d][kv]
    __shared__ __hip_bfloat16 Ps[128][LDX];   // P staging (wave-private strips)

    const int tid  = threadIdx.x;
    const int wave = tid >> 6, lane = tid & 63;
    const int l16  = lane & 15, quad = lane >> 4;
    const int b    = blockIdx.y;
    const int q0   = blockIdx.x * 128;
    const int j0b  = blockIdx.z * (SEQ / NSPLIT);

    bf16x8 qf[2][2];
    #pragma unroll
    for (int s = 0; s < 2; ++s) {
        const __hip_bfloat16* qrow =
            Qb + ((size_t)b * SEQ + q0 + wave * 32 + s * 16 + l16) * HEAD + quad * 8;
        qf[s][0] = *(const bf16x8*)(qrow);
        qf[s][1] = *(const bf16x8*)(qrow + 32);
    }

    const f32x4 z = {0.f, 0.f, 0.f, 0.f};
    f32x4 oacc[2][4] = {{z, z, z, z}, {z, z, z, z}};
    f32x4 lacc[2] = {z, z};

    const __hip_bfloat16 one_bf = __float2bfloat16(1.0f);
    bf16x8 ones;
    #pragma unroll
    for (int j = 0; j < 8; ++j) ones[j] = *(const __bf16*)&one_bf;

    for (int jt = 0; jt < SEQ / NSPLIT; jt += 64) {
        const int j0 = j0b + jt;
        __syncthreads();
        for (int i = tid; i < 512; i += 256) {
            int r = i >> 3, c8 = (i & 7) * 8;
            *(uint4*)&Ks[r][c8] =
                *(const uint4*)(Kb + ((size_t)b * SEQ + j0 + r) * HEAD + c8);
            *(uint4*)&Vs[r][c8] =
                *(const uint4*)(Vt + ((size_t)b * HEAD + r) * SEQ + j0 + c8);
        }
        __syncthreads();

        // S = Q K^T  (wave: 2 strips x 16 q-rows x 64 kv)
        f32x4 sacc[2][4] = {{z, z, z, z}, {z, z, z, z}};
        #pragma unroll
        for (int st = 0; st < 2; ++st) {
            #pragma unroll
            for (int t = 0; t < 4; ++t) {
                bf16x8 kf = *(const bf16x8*)&Ks[t * 16 + l16][st * 32 + quad * 8];
                #pragma unroll
                for (int s = 0; s < 2; ++s)
                    sacc[s][t] = __builtin_amdgcn_mfma_f32_16x16x32_bf16(qf[s][st], kf, sacc[s][t], 0, 0, 0);
            }
        }

        // p = exp2(s)
        #pragma unroll
        for (int s = 0; s < 2; ++s)
            #pragma unroll
            for (int r = 0; r < 4; ++r)
                #pragma unroll
                for (int t = 0; t < 4; ++t) {
                    float p = __builtin_amdgcn_exp2f(sacc[s][t][r]);
                    Ps[wave * 32 + s * 16 + quad * 4 + r][t * 16 + l16] = __float2bfloat16(p);
                }

        // O += P V ; l += P * ones
        #pragma unroll
        for (int s = 0; s < 2; ++s) {
            #pragma unroll
            for (int st = 0; st < 2; ++st) {
                bf16x8 pf = *(const bf16x8*)&Ps[wave * 32 + s * 16 + l16][st * 32 + quad * 8];
                lacc[s] = __builtin_amdgcn_mfma_f32_16x16x32_bf16(pf, ones, lacc[s], 0, 0, 0);
                #pragma unroll
                for (int t = 0; t < 4; ++t) {
                    bf16x8 vf = *(const bf16x8*)&Vs[t * 16 + l16][st * 32 + quad * 8];
                    oacc[s][t] = __builtin_amdgcn_mfma_f32_16x16x32_bf16(pf, vf, oacc[s][t], 0, 0, 0);
                }
            }
        }
    }

    // epilogue: disjoint fp32 partials
    const size_t pb = (size_t)(blockIdx.z * NB + b) * SEQ;
    #pragma unroll
    for (int s = 0; s < 2; ++s) {
        const size_t row0 = pb + q0 + wave * 32 + s * 16 + quad * 4;
        if (l16 == 0) {
            #pragma unroll
            for (int r = 0; r < 4; ++r)
                lp[row0 + r] = lacc[s][r];
        }
        #pragma unroll
        for (int t = 0; t < 4; ++t)
            #pragma unroll
            for (int r = 0; r < 4; ++r)
                Op[(row0 + r) * HEAD + t * 16 + l16] = oacc[s][t][r];
    }
}

// ---------------------------------------------------------------------------
// Merge: out = (sum_s O_s) / (sum_s l_s)
// ---------------------------------------------------------------------------
__global__ __launch_bounds__(256) void merge_kernel(
    const float* __restrict__ Op, const float* __restrict__ lp,
    float* __restrict__ out)
{
    int idx = blockIdx.x * 256 + threadIdx.x;   // [0, B*S*16)
    int bq  = idx >> 4;
    int c4  = (idx & 15) * 4;
    float4 acc = {0.f, 0.f, 0.f, 0.f};
    float  l   = 0.f;
    #pragma unroll
    for (int s = 0; s < NSPLIT; ++s) {
        float4 o = *(const float4*)(Op + ((size_t)s * NB * SEQ + bq) * HEAD + c4);
        acc.x += o.x; acc.y += o.y; acc.z += o.z; acc.w += o.w;
        l += lp[(size_t)s * NB * SEQ + bq];
    }
    float inv = 1.f / l;
    float4 r = {acc.x * inv, acc.y * inv, acc.z * inv, acc.w * inv};
    *(float4*)(out + (size_t)bq * HEAD + c4) = r;
}

extern "C" void kernel_launch(void* const* d_in, const int* in_sizes, int n_in,
                              void* d_out, int out_size, void* d_ws, size_t ws_size,
                              hipStream_t stream) {
    const float* q  = (const float*)d_in[0];
    const float* k  = (const float*)d_in[1];
    const float* v  = (const float*)d_in[2];
    const float* Wq = (const float*)d_in[3];
    const float* Wk = (const float*)d_in[4];
    const float* Wv = (const float*)d_in[5];
    float* out = (float*)d_out;

    // ws: Qb 2MB | Kb 2MB | Vt 2MB | Wc 192KB | Op 32MB | lp 512KB (~38.7MB)
    __hip_bfloat16* Qb = (__hip_bfloat16*)d_ws;
    __hip_bfloat16* Kb = Qb + (size_t)NB * SEQ * HEAD;
    __hip_bfloat16* Vt = Kb + (size_t)NB * SEQ * HEAD;
    __hip_bfloat16* Wc = Vt + (size_t)NB * SEQ * HEAD;
    float* Op = (float*)(Wc + 3 * 64 * EMB);
    float* lp = Op + (size_t)NSPLIT * NB * SEQ * HEAD;

    cvtw_kernel<<<96, 256, 0, stream>>>(Wq, Wk, Wv, Wc);

    dim3 pgrid(NB * SEQ / 64, 3);
    proj_kernel<<<pgrid, dim3(256), 0, stream>>>(q, k, v, Wc, Qb, Kb, Vt);

    dim3 agrid(SEQ / 128, NB, NSPLIT);
    attn_kernel<<<agrid, dim3(256), 0, stream>>>(Qb, Kb, Vt, Op, lp);

    merge_kernel<<<(NB * SEQ * 16) / 256, dim3(256), 0, stream>>>(Op, lp, out);
}